// Round 5
// baseline (296.769 us; speedup 1.0000x reference)
//
#include <hip/hip_runtime.h>
#include <hip/hip_bf16.h>
#include <cstdint>

static constexpr int BLK = 256;

typedef __attribute__((ext_vector_type(8))) short bf16x8;   // 8 bf16 = 4 VGPRs
typedef __attribute__((ext_vector_type(4))) float f32x4;

__device__ __forceinline__ float bf16lo(uint32_t u) { return __uint_as_float(u << 16); }
__device__ __forceinline__ float bf16hi(uint32_t u) { return __uint_as_float(u & 0xffff0000u); }
__device__ __forceinline__ unsigned short f2bf(float f) {
    __hip_bfloat16 h = __float2bfloat16(f);
    return *(unsigned short*)&h;
}

// --------------------------------------------- degree count (fire & forget)-
// 4 edges/thread, 8 independent non-returning atomics -> no wave stall on
// the fabric round-trip.
__global__ __launch_bounds__(BLK) void k_count(const int4* __restrict__ src4,
                                               const int4* __restrict__ dst4,
                                               int* __restrict__ cnt_f,
                                               int* __restrict__ cnt_b, int ne4) {
    int i = blockIdx.x * BLK + threadIdx.x;
    if (i < ne4) {
        int4 s = src4[i], d = dst4[i];
        atomicAdd(cnt_f + d.x, 1); atomicAdd(cnt_f + d.y, 1);
        atomicAdd(cnt_f + d.z, 1); atomicAdd(cnt_f + d.w, 1);
        atomicAdd(cnt_b + s.x, 1); atomicAdd(cnt_b + s.y, 1);
        atomicAdd(cnt_b + s.z, 1); atomicAdd(cnt_b + s.w, 1);
    }
}

// ------------------------------------------- scan level 1 (+ rsqrt fused) --
// grid = 2*nb: first nb blocks scan cnt_f -> off_f (and write dinv_f),
// second nb blocks do the b direction.
__global__ __launch_bounds__(BLK) void k_scan1(const int* __restrict__ cnt_f,
                                               const int* __restrict__ cnt_b,
                                               int* __restrict__ off_f,
                                               int* __restrict__ off_b,
                                               float* __restrict__ dinv_f,
                                               float* __restrict__ dinv_b,
                                               int* __restrict__ bsum_f,
                                               int* __restrict__ bsum_b,
                                               int n, int nb) {
    const int half = blockIdx.x / nb;
    const int blk  = blockIdx.x % nb;
    const int* __restrict__ in   = half ? cnt_b : cnt_f;
    int* __restrict__ out        = half ? off_b : off_f;
    float* __restrict__ dinv     = half ? dinv_b : dinv_f;
    int* __restrict__ bsum       = half ? bsum_b : bsum_f;

    __shared__ int lds[BLK];
    int base = blk * 1024 + threadIdx.x * 4;
    int4 v = make_int4(0, 0, 0, 0);
    if (base < n) v = *(const int4*)(in + base);         // n % 4 == 0
    int tsum = v.x + v.y + v.z + v.w;
    lds[threadIdx.x] = tsum;
    __syncthreads();
    for (int off = 1; off < BLK; off <<= 1) {
        int t = (threadIdx.x >= off) ? lds[threadIdx.x - off] : 0;
        __syncthreads();
        lds[threadIdx.x] += t;
        __syncthreads();
    }
    int excl = lds[threadIdx.x] - tsum;
    if (base < n) {
        *(int4*)(out + base) = make_int4(excl, excl + v.x, excl + v.x + v.y,
                                         excl + v.x + v.y + v.z);
        *(float4*)(dinv + base) = make_float4(rsqrtf(1.0f + (float)v.x),
                                              rsqrtf(1.0f + (float)v.y),
                                              rsqrtf(1.0f + (float)v.z),
                                              rsqrtf(1.0f + (float)v.w));
    }
    if (threadIdx.x == BLK - 1) bsum[blk] = excl + tsum;
}

// ------------------------------------------------------------ scan level 2 -
__global__ __launch_bounds__(BLK) void k_scan2(int* __restrict__ bsum_f,
                                               int* __restrict__ bsum_b, int nb) {
    int* __restrict__ bsum = blockIdx.x ? bsum_b : bsum_f;
    __shared__ int lds[BLK];
    int v = (threadIdx.x < nb) ? bsum[threadIdx.x] : 0;
    lds[threadIdx.x] = v;
    __syncthreads();
    for (int off = 1; off < BLK; off <<= 1) {
        int t = (threadIdx.x >= off) ? lds[threadIdx.x - off] : 0;
        __syncthreads();
        lds[threadIdx.x] += t;
        __syncthreads();
    }
    if (threadIdx.x < nb) bsum[threadIdx.x] = lds[threadIdx.x] - v;
}

// -------------------------------------- scan level 3 (+ cursor duplicate) --
__global__ __launch_bounds__(BLK) void k_scan3(int* __restrict__ off_f,
                                               int* __restrict__ off_b,
                                               int* __restrict__ cur_f,
                                               int* __restrict__ cur_b,
                                               const int* __restrict__ bsum_f,
                                               const int* __restrict__ bsum_b,
                                               int n, int ne, int gn) {
    const int half = blockIdx.x / gn;
    const int blk  = blockIdx.x % gn;
    int* __restrict__ off        = half ? off_b : off_f;
    int* __restrict__ cur        = half ? cur_b : cur_f;
    const int* __restrict__ bsum = half ? bsum_b : bsum_f;
    int i = blk * BLK + threadIdx.x;
    if (i < n) {
        int v = off[i] + bsum[i >> 10];
        off[i] = v;
        cur[i] = v;
    }
    if (i == 0) off[n] = ne;
}

// ------------------------------------------------ CSR fill (cursor-based) --
// 4 edges/thread: 8 independent atomic-returns in flight, then 8 stores.
__global__ __launch_bounds__(BLK) void k_fill(const int4* __restrict__ src4,
                                              const int4* __restrict__ dst4,
                                              int* __restrict__ cur_f,
                                              int* __restrict__ cur_b,
                                              int* __restrict__ adj_f,
                                              int* __restrict__ adj_b, int ne4) {
    int i = blockIdx.x * BLK + threadIdx.x;
    if (i < ne4) {
        int4 s = src4[i], d = dst4[i];
        int pf0 = atomicAdd(cur_f + d.x, 1);
        int pf1 = atomicAdd(cur_f + d.y, 1);
        int pf2 = atomicAdd(cur_f + d.z, 1);
        int pf3 = atomicAdd(cur_f + d.w, 1);
        int pb0 = atomicAdd(cur_b + s.x, 1);
        int pb1 = atomicAdd(cur_b + s.y, 1);
        int pb2 = atomicAdd(cur_b + s.z, 1);
        int pb3 = atomicAdd(cur_b + s.w, 1);
        adj_f[pf0] = s.x; adj_f[pf1] = s.y; adj_f[pf2] = s.z; adj_f[pf3] = s.w;
        adj_b[pb0] = d.x; adj_b[pb1] = d.y; adj_b[pb2] = d.z; adj_b[pb3] = d.w;
    }
}

// ----------------------------------- x -> bf16  AND  W -> bf16 transposed --
// blocks [0,gx): x conversion; blocks [gx,gx+8): W transpose slices.
__global__ __launch_bounds__(BLK) void k_cvt(const float4* __restrict__ x4,
                                             ushort4* __restrict__ xb4, int total4,
                                             const float* __restrict__ Wf,
                                             const float* __restrict__ Wb,
                                             unsigned short* __restrict__ WTf,
                                             unsigned short* __restrict__ WTb,
                                             int gx) {
    if ((int)blockIdx.x >= gx) {
        int wb = blockIdx.x - gx;                   // 0..7
        for (int idx = wb * 2048 + threadIdx.x; idx < (wb + 1) * 2048; idx += BLK) {
            int c = idx >> 7, k = idx & 127;
            WTf[c * 128 + k] = f2bf(Wf[k * 128 + c]);
            WTb[c * 128 + k] = f2bf(Wb[k * 128 + c]);
        }
        return;
    }
    int i = blockIdx.x * BLK + threadIdx.x;
    if (i < total4) {
        float4 v = x4[i];
        ushort4 o;
        o.x = f2bf(v.x); o.y = f2bf(v.y); o.z = f2bf(v.z); o.w = f2bf(v.w);
        xb4[i] = o;
    }
}

// ------------------------------------------------------------ MFMA GEMM ----
__global__ __launch_bounds__(BLK) void k_gemm_mfma(
        const unsigned short* __restrict__ xb,
        const unsigned short* __restrict__ WTf,
        const unsigned short* __restrict__ WTb,
        const float* __restrict__ dinv_f,
        const float* __restrict__ dinv_b,
        unsigned short* __restrict__ hs_f,
        unsigned short* __restrict__ hs_b, int n) {
    const int wave = threadIdx.x >> 6;
    const int lane = threadIdx.x & 63;
    const int conv = wave >> 1;
    const int n0   = (wave & 1) * 64;
    const int m0   = blockIdx.x * 16;
    const int q    = lane >> 4;
    const int t16  = lane & 15;

    const unsigned short* __restrict__ WT = conv ? WTb : WTf;
    const float* __restrict__ dinv        = conv ? dinv_b : dinv_f;
    unsigned short* __restrict__ hs       = conv ? hs_b : hs_f;

    int arow = m0 + t16; if (arow >= n) arow = n - 1;
    bf16x8 a[4];
#pragma unroll
    for (int s = 0; s < 4; ++s)
        a[s] = *(const bf16x8*)(xb + (size_t)arow * 128 + s * 32 + q * 8);

    const float4 dv = *(const float4*)(dinv + m0 + q * 4);

#pragma unroll
    for (int t = 0; t < 4; ++t) {
        const unsigned short* wrow = WT + (size_t)(n0 + t * 16 + t16) * 128;
        f32x4 c = {0.f, 0.f, 0.f, 0.f};
#pragma unroll
        for (int s = 0; s < 4; ++s) {
            bf16x8 b = *(const bf16x8*)(wrow + s * 32 + q * 8);
            c = __builtin_amdgcn_mfma_f32_16x16x32_bf16(a[s], b, c, 0, 0, 0);
        }
#pragma unroll
        for (int r = 0; r < 4; ++r) {
            int row = m0 + q * 4 + r;
            if (row < n) {
                float vr = (r == 0 ? dv.x : r == 1 ? dv.y : r == 2 ? dv.z : dv.w);
                hs[(size_t)row * 128 + n0 + t * 16 + t16] = f2bf(c[r] * vr);
            }
        }
    }
}

// ------------------------------------------------------------ gather -------
// wave per node, lane owns a bf16x2 dword; 8-wide independent row fetches.
__global__ __launch_bounds__(BLK) void k_gather(const int* __restrict__ off_f,
                                                const int* __restrict__ adj_f,
                                                const int* __restrict__ off_b,
                                                const int* __restrict__ adj_b,
                                                const uint32_t* __restrict__ hsf,
                                                const uint32_t* __restrict__ hsb,
                                                const float* __restrict__ dinv_f,
                                                const float* __restrict__ dinv_b,
                                                const float* __restrict__ bf,
                                                const float* __restrict__ bb,
                                                float* __restrict__ out, int n) {
    const int wave = threadIdx.x >> 6;
    const int lane = threadIdx.x & 63;
    const int node = blockIdx.x * 4 + wave;
    if (node >= n) return;

    float f0, f1, g0, g1;
    {
        uint32_t u = hsf[(size_t)node * 64 + lane];
        f0 = bf16lo(u); f1 = bf16hi(u);
        int jb = off_f[node], je = off_f[node + 1];
        for (int b = jb; b < je; b += 64) {
            int m = min(64, je - b);
            int idx = (lane < m) ? adj_f[b + lane] : 0;
            int j = 0;
            for (; j + 8 <= m; j += 8) {
                int n0 = __shfl(idx, j + 0), n1 = __shfl(idx, j + 1);
                int n2 = __shfl(idx, j + 2), n3 = __shfl(idx, j + 3);
                int n4 = __shfl(idx, j + 4), n5 = __shfl(idx, j + 5);
                int n6 = __shfl(idx, j + 6), n7 = __shfl(idx, j + 7);
                uint32_t u0 = hsf[(size_t)n0 * 64 + lane];
                uint32_t u1 = hsf[(size_t)n1 * 64 + lane];
                uint32_t u2 = hsf[(size_t)n2 * 64 + lane];
                uint32_t u3 = hsf[(size_t)n3 * 64 + lane];
                uint32_t u4 = hsf[(size_t)n4 * 64 + lane];
                uint32_t u5 = hsf[(size_t)n5 * 64 + lane];
                uint32_t u6 = hsf[(size_t)n6 * 64 + lane];
                uint32_t u7 = hsf[(size_t)n7 * 64 + lane];
                f0 += bf16lo(u0) + bf16lo(u1) + bf16lo(u2) + bf16lo(u3)
                    + bf16lo(u4) + bf16lo(u5) + bf16lo(u6) + bf16lo(u7);
                f1 += bf16hi(u0) + bf16hi(u1) + bf16hi(u2) + bf16hi(u3)
                    + bf16hi(u4) + bf16hi(u5) + bf16hi(u6) + bf16hi(u7);
            }
            for (; j + 4 <= m; j += 4) {
                int n0 = __shfl(idx, j + 0), n1 = __shfl(idx, j + 1);
                int n2 = __shfl(idx, j + 2), n3 = __shfl(idx, j + 3);
                uint32_t u0 = hsf[(size_t)n0 * 64 + lane];
                uint32_t u1 = hsf[(size_t)n1 * 64 + lane];
                uint32_t u2 = hsf[(size_t)n2 * 64 + lane];
                uint32_t u3 = hsf[(size_t)n3 * 64 + lane];
                f0 += bf16lo(u0) + bf16lo(u1) + bf16lo(u2) + bf16lo(u3);
                f1 += bf16hi(u0) + bf16hi(u1) + bf16hi(u2) + bf16hi(u3);
            }
            for (; j < m; ++j) {
                uint32_t uj = hsf[(size_t)__shfl(idx, j) * 64 + lane];
                f0 += bf16lo(uj); f1 += bf16hi(uj);
            }
        }
        float s = dinv_f[node];
        f0 *= s; f1 *= s;
    }
    {
        uint32_t u = hsb[(size_t)node * 64 + lane];
        g0 = bf16lo(u); g1 = bf16hi(u);
        int jb = off_b[node], je = off_b[node + 1];
        for (int b = jb; b < je; b += 64) {
            int m = min(64, je - b);
            int idx = (lane < m) ? adj_b[b + lane] : 0;
            int j = 0;
            for (; j + 8 <= m; j += 8) {
                int n0 = __shfl(idx, j + 0), n1 = __shfl(idx, j + 1);
                int n2 = __shfl(idx, j + 2), n3 = __shfl(idx, j + 3);
                int n4 = __shfl(idx, j + 4), n5 = __shfl(idx, j + 5);
                int n6 = __shfl(idx, j + 6), n7 = __shfl(idx, j + 7);
                uint32_t u0 = hsb[(size_t)n0 * 64 + lane];
                uint32_t u1 = hsb[(size_t)n1 * 64 + lane];
                uint32_t u2 = hsb[(size_t)n2 * 64 + lane];
                uint32_t u3 = hsb[(size_t)n3 * 64 + lane];
                uint32_t u4 = hsb[(size_t)n4 * 64 + lane];
                uint32_t u5 = hsb[(size_t)n5 * 64 + lane];
                uint32_t u6 = hsb[(size_t)n6 * 64 + lane];
                uint32_t u7 = hsb[(size_t)n7 * 64 + lane];
                g0 += bf16lo(u0) + bf16lo(u1) + bf16lo(u2) + bf16lo(u3)
                    + bf16lo(u4) + bf16lo(u5) + bf16lo(u6) + bf16lo(u7);
                g1 += bf16hi(u0) + bf16hi(u1) + bf16hi(u2) + bf16hi(u3)
                    + bf16hi(u4) + bf16hi(u5) + bf16hi(u6) + bf16hi(u7);
            }
            for (; j + 4 <= m; j += 4) {
                int n0 = __shfl(idx, j + 0), n1 = __shfl(idx, j + 1);
                int n2 = __shfl(idx, j + 2), n3 = __shfl(idx, j + 3);
                uint32_t u0 = hsb[(size_t)n0 * 64 + lane];
                uint32_t u1 = hsb[(size_t)n1 * 64 + lane];
                uint32_t u2 = hsb[(size_t)n2 * 64 + lane];
                uint32_t u3 = hsb[(size_t)n3 * 64 + lane];
                g0 += bf16lo(u0) + bf16lo(u1) + bf16lo(u2) + bf16lo(u3);
                g1 += bf16hi(u0) + bf16hi(u1) + bf16hi(u2) + bf16hi(u3);
            }
            for (; j < m; ++j) {
                uint32_t uj = hsb[(size_t)__shfl(idx, j) * 64 + lane];
                g0 += bf16lo(uj); g1 += bf16hi(uj);
            }
        }
        float s = dinv_b[node];
        g0 *= s; g1 *= s;
    }

    const float2 biasf = ((const float2*)bf)[lane];
    const float2 biasb = ((const float2*)bb)[lane];
    float v0 = f0 + g0 + biasf.x + biasb.x;
    float v1 = f1 + g1 + biasf.y + biasb.y;
    ((float2*)out)[(size_t)node * 64 + lane] =
        make_float2(fmaxf(v0, 0.0f), fmaxf(v1, 0.0f));
}

// ------------------------------------------------------------ launcher -----
extern "C" void kernel_launch(void* const* d_in, const int* in_sizes, int n_in,
                              void* d_out, int out_size, void* d_ws, size_t ws_size,
                              hipStream_t stream) {
    const float* x  = (const float*)d_in[0];
    const int*   ei = (const int*)d_in[1];
    const float* Wf = (const float*)d_in[2];
    const float* bf = (const float*)d_in[3];
    const float* Wb = (const float*)d_in[4];
    const float* bb = (const float*)d_in[5];

    const int n  = in_sizes[0] / 128;   // 50000
    const int ne = in_sizes[1] / 2;     // 625000
    const int* src = ei;
    const int* dst = ei + ne;
    float* out = (float*)d_out;

    // workspace layout (16B-aligned chunks; n and ne are multiples of 4)
    char* w = (char*)d_ws;
    float* dinv_f = (float*)w;                      w += (size_t)n * 4;
    float* dinv_b = (float*)w;                      w += (size_t)n * 4;
    unsigned short* hs_f = (unsigned short*)w;      w += (size_t)n * 128 * 2;
    unsigned short* hs_b = (unsigned short*)w;      w += (size_t)n * 128 * 2;
    unsigned short* xb   = (unsigned short*)w;      w += (size_t)n * 128 * 2;
    unsigned short* WTf  = (unsigned short*)w;      w += 128 * 128 * 2;
    unsigned short* WTb  = (unsigned short*)w;      w += 128 * 128 * 2;
    int*   cnt_f  = (int*)w;                        w += (size_t)n * 4;   // cnt_f+cnt_b
    int*   cnt_b  = (int*)w;                        w += (size_t)n * 4;   // contiguous
    int*   off_f  = (int*)w;                        w += (size_t)(n + 4) * 4;
    int*   off_b  = (int*)w;                        w += (size_t)(n + 4) * 4;
    int*   cur_f  = (int*)w;                        w += (size_t)n * 4;
    int*   cur_b  = (int*)w;                        w += (size_t)n * 4;
    int*   adj_f  = (int*)w;                        w += (size_t)ne * 4;
    int*   adj_b  = (int*)w;                        w += (size_t)ne * 4;
    int*   bsum_f = (int*)w;                        w += 256 * 4;
    int*   bsum_b = (int*)w;                        w += 256 * 4;

    const int gn  = (n + BLK - 1) / BLK;
    const int nb  = (n + 1023) / 1024;
    const int ne4 = ne / 4;                          // 156250
    const int ge4 = (ne4 + BLK - 1) / BLK;
    const int total4 = n * 32;
    const int gx  = (total4 + BLK - 1) / BLK;

    hipMemsetAsync(cnt_f, 0, (size_t)2 * n * 4, stream);   // cnt_f + cnt_b

    k_count <<<ge4, BLK, 0, stream>>>((const int4*)src, (const int4*)dst,
                                      cnt_f, cnt_b, ne4);
    k_scan1 <<<2 * nb, BLK, 0, stream>>>(cnt_f, cnt_b, off_f, off_b,
                                         dinv_f, dinv_b, bsum_f, bsum_b, n, nb);
    k_scan2 <<<2, BLK, 0, stream>>>(bsum_f, bsum_b, nb);
    k_scan3 <<<2 * gn, BLK, 0, stream>>>(off_f, off_b, cur_f, cur_b,
                                         bsum_f, bsum_b, n, ne, gn);
    k_fill  <<<ge4, BLK, 0, stream>>>((const int4*)src, (const int4*)dst,
                                      cur_f, cur_b, adj_f, adj_b, ne4);

    k_cvt   <<<gx + 8, BLK, 0, stream>>>((const float4*)x, (ushort4*)xb, total4,
                                         Wf, Wb, WTf, WTb, gx);

    k_gemm_mfma<<<(n + 15) / 16, BLK, 0, stream>>>(xb, WTf, WTb, dinv_f, dinv_b,
                                                   hs_f, hs_b, n);

    k_gather<<<(n + 3) / 4, BLK, 0, stream>>>(off_f, adj_f, off_b, adj_b,
                                              (const uint32_t*)hs_f,
                                              (const uint32_t*)hs_b,
                                              dinv_f, dinv_b, bf, bb, out, n);
}

// Round 6
// 281.417 us; speedup vs baseline: 1.0546x; 1.0546x over previous
//
#include <hip/hip_runtime.h>
#include <hip/hip_bf16.h>
#include <cstdint>

static constexpr int BLK = 256;

typedef __attribute__((ext_vector_type(8))) short bf16x8;   // 8 bf16 = 4 VGPRs
typedef __attribute__((ext_vector_type(4))) float f32x4;

__device__ __forceinline__ float bf16lo(uint32_t u) { return __uint_as_float(u << 16); }
__device__ __forceinline__ float bf16hi(uint32_t u) { return __uint_as_float(u & 0xffff0000u); }
__device__ __forceinline__ unsigned short f2bf(float f) {
    __hip_bfloat16 h = __float2bfloat16(f);
    return *(unsigned short*)&h;
}

// ============================================================ PHASE 1 ======
// blocks [0, gc):          rank-count — 1 edge/thread, atomic-returns give
//                          both degree and within-bucket rank (round-4 win;
//                          full grid keeps max waves resident = max
//                          outstanding atomics, the round-5 lesson).
// blocks [gc, gc+gx):      x -> bf16 (float4 -> ushort4)
// blocks [gc+gx, +8):      W -> bf16 transposed to [n][k]
// Independent parts co-scheduled: cvt's BW work hides under atomic latency.
__global__ __launch_bounds__(BLK) void k_phase1(
        const int* __restrict__ src, const int* __restrict__ dst,
        int* __restrict__ cnt_f, int* __restrict__ cnt_b,
        int* __restrict__ rank_f, int* __restrict__ rank_b, int ne,
        const float4* __restrict__ x4, ushort4* __restrict__ xb4, int total4,
        const float* __restrict__ Wf, const float* __restrict__ Wb,
        unsigned short* __restrict__ WTf, unsigned short* __restrict__ WTb,
        int gc, int gx) {
    const int bid = blockIdx.x;
    if (bid < gc) {
        int e = bid * BLK + threadIdx.x;
        if (e < ne) {
            int d = dst[e], s = src[e];
            rank_f[e] = atomicAdd(cnt_f + d, 1);
            rank_b[e] = atomicAdd(cnt_b + s, 1);
        }
        return;
    }
    if (bid < gc + gx) {
        int i = (bid - gc) * BLK + threadIdx.x;
        if (i < total4) {
            float4 v = x4[i];
            ushort4 o;
            o.x = f2bf(v.x); o.y = f2bf(v.y); o.z = f2bf(v.z); o.w = f2bf(v.w);
            xb4[i] = o;
        }
        return;
    }
    int wb = bid - gc - gx;                      // 0..7
    for (int idx = wb * 2048 + threadIdx.x; idx < (wb + 1) * 2048; idx += BLK) {
        int c = idx >> 7, k = idx & 127;
        WTf[c * 128 + k] = f2bf(Wf[k * 128 + c]);
        WTb[c * 128 + k] = f2bf(Wb[k * 128 + c]);
    }
}

// ============================================================ PHASE 2 ======
// blocks 0,1:   full exclusive scan of cnt -> off (sequential 1024-chunk
//               carry loop; one block per direction) + fused rsqrt -> dinv.
//               ~10 us, hidden under the GEMM blocks.
// blocks 2..:   MFMA GEMM  hs = bf16(dinv * (xb @ W))
__global__ __launch_bounds__(BLK) void k_phase2(
        const int* __restrict__ cnt_f, const int* __restrict__ cnt_b,
        int* __restrict__ off_f, int* __restrict__ off_b,
        float* __restrict__ dinv_f, float* __restrict__ dinv_b, int n, int ne,
        const unsigned short* __restrict__ xb,
        const unsigned short* __restrict__ WTf,
        const unsigned short* __restrict__ WTb,
        unsigned short* __restrict__ hs_f, unsigned short* __restrict__ hs_b) {
    const int bid = blockIdx.x;
    if (bid < 2) {
        // ---- serial-carry scan, one block per direction ----
        const int* __restrict__ in = bid ? cnt_b : cnt_f;
        int* __restrict__ off      = bid ? off_b : off_f;
        float* __restrict__ dinv   = bid ? dinv_b : dinv_f;
        __shared__ int lds[BLK];
        __shared__ int carry_s;
        if (threadIdx.x == 0) carry_s = 0;
        __syncthreads();
        for (int base0 = 0; base0 < n; base0 += 1024) {
            int i = base0 + threadIdx.x * 4;
            int4 v = make_int4(0, 0, 0, 0);
            if (i < n) v = *(const int4*)(in + i);        // n % 4 == 0
            int tsum = v.x + v.y + v.z + v.w;
            lds[threadIdx.x] = tsum;
            __syncthreads();
            for (int o = 1; o < BLK; o <<= 1) {
                int t = (threadIdx.x >= o) ? lds[threadIdx.x - o] : 0;
                __syncthreads();
                lds[threadIdx.x] += t;
                __syncthreads();
            }
            int carry = carry_s;
            int excl = carry + lds[threadIdx.x] - tsum;
            if (i < n) {
                *(int4*)(off + i) = make_int4(excl, excl + v.x,
                                              excl + v.x + v.y,
                                              excl + v.x + v.y + v.z);
                *(float4*)(dinv + i) = make_float4(rsqrtf(1.0f + (float)v.x),
                                                   rsqrtf(1.0f + (float)v.y),
                                                   rsqrtf(1.0f + (float)v.z),
                                                   rsqrtf(1.0f + (float)v.w));
            }
            __syncthreads();
            if (threadIdx.x == BLK - 1) carry_s = carry + lds[BLK - 1];
            __syncthreads();
        }
        if (threadIdx.x == 0) off[n] = ne;
        return;
    }
    // ---- MFMA GEMM ----
    const int wave = threadIdx.x >> 6;
    const int lane = threadIdx.x & 63;
    const int conv = wave >> 1;
    const int n0   = (wave & 1) * 64;
    const int m0   = (bid - 2) * 16;
    const int q    = lane >> 4;
    const int t16  = lane & 15;

    const unsigned short* __restrict__ WT = conv ? WTb : WTf;
    const float* __restrict__ dinv        = conv ? dinv_b : dinv_f;
    unsigned short* __restrict__ hs       = conv ? hs_b : hs_f;

    int arow = m0 + t16; if (arow >= n) arow = n - 1;
    bf16x8 a[4];
#pragma unroll
    for (int s = 0; s < 4; ++s)
        a[s] = *(const bf16x8*)(xb + (size_t)arow * 128 + s * 32 + q * 8);

    // dinv for this conv comes from the scan blocks? No — dinv is written by
    // blocks 0/1 of THIS dispatch; GEMM blocks may run first. Avoid the race:
    // apply dinv later is wrong too. Instead recompute dinv from cnt (cheap,
    // no dependency on the scan blocks).
    const int mrow = m0 + q * 4;
    const int4 cv = *(const int4*)((conv ? cnt_b : cnt_f) + mrow);
    float dvr[4] = { rsqrtf(1.0f + (float)cv.x), rsqrtf(1.0f + (float)cv.y),
                     rsqrtf(1.0f + (float)cv.z), rsqrtf(1.0f + (float)cv.w) };

#pragma unroll
    for (int t = 0; t < 4; ++t) {
        const unsigned short* wrow = WT + (size_t)(n0 + t * 16 + t16) * 128;
        f32x4 c = {0.f, 0.f, 0.f, 0.f};
#pragma unroll
        for (int s = 0; s < 4; ++s) {
            bf16x8 b = *(const bf16x8*)(wrow + s * 32 + q * 8);
            c = __builtin_amdgcn_mfma_f32_16x16x32_bf16(a[s], b, c, 0, 0, 0);
        }
#pragma unroll
        for (int r = 0; r < 4; ++r) {
            int row = m0 + q * 4 + r;
            if (row < n)
                hs[(size_t)row * 128 + n0 + t * 16 + t16] = f2bf(c[r] * dvr[r]);
        }
    }
}

// ============================================================ CSR fill =====
// atomic-free via ranks; 1 edge/thread, full grid (max resident waves).
__global__ __launch_bounds__(BLK) void k_fill(
        const int* __restrict__ src, const int* __restrict__ dst,
        const int* __restrict__ off_f, const int* __restrict__ off_b,
        const int* __restrict__ rank_f, const int* __restrict__ rank_b,
        int* __restrict__ adj_f, int* __restrict__ adj_b, int ne) {
    int e = blockIdx.x * BLK + threadIdx.x;
    if (e < ne) {
        int s = src[e], d = dst[e];
        adj_f[off_f[d] + rank_f[e]] = s;
        adj_b[off_b[s] + rank_b[e]] = d;
    }
}

// ============================================================ gather =======
__global__ __launch_bounds__(BLK) void k_gather(const int* __restrict__ off_f,
                                                const int* __restrict__ adj_f,
                                                const int* __restrict__ off_b,
                                                const int* __restrict__ adj_b,
                                                const uint32_t* __restrict__ hsf,
                                                const uint32_t* __restrict__ hsb,
                                                const float* __restrict__ dinv_f,
                                                const float* __restrict__ dinv_b,
                                                const float* __restrict__ bf,
                                                const float* __restrict__ bb,
                                                float* __restrict__ out, int n) {
    const int wave = threadIdx.x >> 6;
    const int lane = threadIdx.x & 63;
    const int node = blockIdx.x * 4 + wave;
    if (node >= n) return;

    float f0, f1, g0, g1;
    {
        uint32_t u = hsf[(size_t)node * 64 + lane];
        f0 = bf16lo(u); f1 = bf16hi(u);
        int jb = off_f[node], je = off_f[node + 1];
        for (int b = jb; b < je; b += 64) {
            int m = min(64, je - b);
            int idx = (lane < m) ? adj_f[b + lane] : 0;
            int j = 0;
            for (; j + 8 <= m; j += 8) {
                int n0 = __shfl(idx, j + 0), n1 = __shfl(idx, j + 1);
                int n2 = __shfl(idx, j + 2), n3 = __shfl(idx, j + 3);
                int n4 = __shfl(idx, j + 4), n5 = __shfl(idx, j + 5);
                int n6 = __shfl(idx, j + 6), n7 = __shfl(idx, j + 7);
                uint32_t u0 = hsf[(size_t)n0 * 64 + lane];
                uint32_t u1 = hsf[(size_t)n1 * 64 + lane];
                uint32_t u2 = hsf[(size_t)n2 * 64 + lane];
                uint32_t u3 = hsf[(size_t)n3 * 64 + lane];
                uint32_t u4 = hsf[(size_t)n4 * 64 + lane];
                uint32_t u5 = hsf[(size_t)n5 * 64 + lane];
                uint32_t u6 = hsf[(size_t)n6 * 64 + lane];
                uint32_t u7 = hsf[(size_t)n7 * 64 + lane];
                f0 += bf16lo(u0) + bf16lo(u1) + bf16lo(u2) + bf16lo(u3)
                    + bf16lo(u4) + bf16lo(u5) + bf16lo(u6) + bf16lo(u7);
                f1 += bf16hi(u0) + bf16hi(u1) + bf16hi(u2) + bf16hi(u3)
                    + bf16hi(u4) + bf16hi(u5) + bf16hi(u6) + bf16hi(u7);
            }
            for (; j + 4 <= m; j += 4) {
                int n0 = __shfl(idx, j + 0), n1 = __shfl(idx, j + 1);
                int n2 = __shfl(idx, j + 2), n3 = __shfl(idx, j + 3);
                uint32_t u0 = hsf[(size_t)n0 * 64 + lane];
                uint32_t u1 = hsf[(size_t)n1 * 64 + lane];
                uint32_t u2 = hsf[(size_t)n2 * 64 + lane];
                uint32_t u3 = hsf[(size_t)n3 * 64 + lane];
                f0 += bf16lo(u0) + bf16lo(u1) + bf16lo(u2) + bf16lo(u3);
                f1 += bf16hi(u0) + bf16hi(u1) + bf16hi(u2) + bf16hi(u3);
            }
            for (; j < m; ++j) {
                uint32_t uj = hsf[(size_t)__shfl(idx, j) * 64 + lane];
                f0 += bf16lo(uj); f1 += bf16hi(uj);
            }
        }
        float s = dinv_f[node];
        f0 *= s; f1 *= s;
    }
    {
        uint32_t u = hsb[(size_t)node * 64 + lane];
        g0 = bf16lo(u); g1 = bf16hi(u);
        int jb = off_b[node], je = off_b[node + 1];
        for (int b = jb; b < je; b += 64) {
            int m = min(64, je - b);
            int idx = (lane < m) ? adj_b[b + lane] : 0;
            int j = 0;
            for (; j + 8 <= m; j += 8) {
                int n0 = __shfl(idx, j + 0), n1 = __shfl(idx, j + 1);
                int n2 = __shfl(idx, j + 2), n3 = __shfl(idx, j + 3);
                int n4 = __shfl(idx, j + 4), n5 = __shfl(idx, j + 5);
                int n6 = __shfl(idx, j + 6), n7 = __shfl(idx, j + 7);
                uint32_t u0 = hsb[(size_t)n0 * 64 + lane];
                uint32_t u1 = hsb[(size_t)n1 * 64 + lane];
                uint32_t u2 = hsb[(size_t)n2 * 64 + lane];
                uint32_t u3 = hsb[(size_t)n3 * 64 + lane];
                uint32_t u4 = hsb[(size_t)n4 * 64 + lane];
                uint32_t u5 = hsb[(size_t)n5 * 64 + lane];
                uint32_t u6 = hsb[(size_t)n6 * 64 + lane];
                uint32_t u7 = hsb[(size_t)n7 * 64 + lane];
                g0 += bf16lo(u0) + bf16lo(u1) + bf16lo(u2) + bf16lo(u3)
                    + bf16lo(u4) + bf16lo(u5) + bf16lo(u6) + bf16lo(u7);
                g1 += bf16hi(u0) + bf16hi(u1) + bf16hi(u2) + bf16hi(u3)
                    + bf16hi(u4) + bf16hi(u5) + bf16hi(u6) + bf16hi(u7);
            }
            for (; j + 4 <= m; j += 4) {
                int n0 = __shfl(idx, j + 0), n1 = __shfl(idx, j + 1);
                int n2 = __shfl(idx, j + 2), n3 = __shfl(idx, j + 3);
                uint32_t u0 = hsb[(size_t)n0 * 64 + lane];
                uint32_t u1 = hsb[(size_t)n1 * 64 + lane];
                uint32_t u2 = hsb[(size_t)n2 * 64 + lane];
                uint32_t u3 = hsb[(size_t)n3 * 64 + lane];
                g0 += bf16lo(u0) + bf16lo(u1) + bf16lo(u2) + bf16lo(u3);
                g1 += bf16hi(u0) + bf16hi(u1) + bf16hi(u2) + bf16hi(u3);
            }
            for (; j < m; ++j) {
                uint32_t uj = hsb[(size_t)__shfl(idx, j) * 64 + lane];
                g0 += bf16lo(uj); g1 += bf16hi(uj);
            }
        }
        float s = dinv_b[node];
        g0 *= s; g1 *= s;
    }

    const float2 biasf = ((const float2*)bf)[lane];
    const float2 biasb = ((const float2*)bb)[lane];
    float v0 = f0 + g0 + biasf.x + biasb.x;
    float v1 = f1 + g1 + biasf.y + biasb.y;
    ((float2*)out)[(size_t)node * 64 + lane] =
        make_float2(fmaxf(v0, 0.0f), fmaxf(v1, 0.0f));
}

// ============================================================ launcher =====
extern "C" void kernel_launch(void* const* d_in, const int* in_sizes, int n_in,
                              void* d_out, int out_size, void* d_ws, size_t ws_size,
                              hipStream_t stream) {
    const float* x  = (const float*)d_in[0];
    const int*   ei = (const int*)d_in[1];
    const float* Wf = (const float*)d_in[2];
    const float* bf = (const float*)d_in[3];
    const float* Wb = (const float*)d_in[4];
    const float* bb = (const float*)d_in[5];

    const int n  = in_sizes[0] / 128;   // 50000
    const int ne = in_sizes[1] / 2;     // 625000
    const int* src = ei;
    const int* dst = ei + ne;
    float* out = (float*)d_out;

    // workspace layout (16B-aligned; n, ne multiples of 4)
    char* w = (char*)d_ws;
    float* dinv_f = (float*)w;                      w += (size_t)n * 4;
    float* dinv_b = (float*)w;                      w += (size_t)n * 4;
    unsigned short* hs_f = (unsigned short*)w;      w += (size_t)n * 128 * 2;
    unsigned short* hs_b = (unsigned short*)w;      w += (size_t)n * 128 * 2;
    unsigned short* xb   = (unsigned short*)w;      w += (size_t)n * 128 * 2;
    unsigned short* WTf  = (unsigned short*)w;      w += 128 * 128 * 2;
    unsigned short* WTb  = (unsigned short*)w;      w += 128 * 128 * 2;
    int*   cnt_f  = (int*)w;                        w += (size_t)n * 4;   // contiguous
    int*   cnt_b  = (int*)w;                        w += (size_t)n * 4;   //  with cnt_f
    int*   off_f  = (int*)w;                        w += (size_t)(n + 4) * 4;
    int*   off_b  = (int*)w;                        w += (size_t)(n + 4) * 4;
    int*   rank_f = (int*)w;                        w += (size_t)ne * 4;
    int*   rank_b = (int*)w;                        w += (size_t)ne * 4;
    int*   adj_f  = (int*)w;                        w += (size_t)ne * 4;
    int*   adj_b  = (int*)w;                        w += (size_t)ne * 4;

    const int gc = (ne + BLK - 1) / BLK;            // 2442 count blocks
    const int total4 = n * 32;
    const int gx = (total4 + BLK - 1) / BLK;        // 6250 cvt blocks
    const int gg = (n + 15) / 16;                   // 3125 gemm blocks

    hipMemsetAsync(cnt_f, 0, (size_t)2 * n * 4, stream);

    k_phase1<<<gc + gx + 8, BLK, 0, stream>>>(src, dst, cnt_f, cnt_b,
                                              rank_f, rank_b, ne,
                                              (const float4*)x, (ushort4*)xb, total4,
                                              Wf, Wb, WTf, WTb, gc, gx);

    k_phase2<<<2 + gg, BLK, 0, stream>>>(cnt_f, cnt_b, off_f, off_b,
                                         dinv_f, dinv_b, n, ne,
                                         xb, WTf, WTb, hs_f, hs_b);

    k_fill  <<<gc, BLK, 0, stream>>>(src, dst, off_f, off_b, rank_f, rank_b,
                                     adj_f, adj_b, ne);

    k_gather<<<(n + 3) / 4, BLK, 0, stream>>>(off_f, adj_f, off_b, adj_b,
                                              (const uint32_t*)hs_f,
                                              (const uint32_t*)hs_b,
                                              dinv_f, dinv_b, bf, bb, out, n);
}

// Round 7
// 245.119 us; speedup vs baseline: 1.2107x; 1.1481x over previous
//
#include <hip/hip_runtime.h>
#include <hip/hip_bf16.h>
#include <cstdint>

static constexpr int BLK = 256;

typedef __attribute__((ext_vector_type(8))) short bf16x8;   // 8 bf16 = 4 VGPRs
typedef __attribute__((ext_vector_type(4))) float f32x4;

__device__ __forceinline__ float bf16lo(uint32_t u) { return __uint_as_float(u << 16); }
__device__ __forceinline__ float bf16hi(uint32_t u) { return __uint_as_float(u & 0xffff0000u); }
__device__ __forceinline__ unsigned short f2bf(float f) {
    __hip_bfloat16 h = __float2bfloat16(f);
    return *(unsigned short*)&h;
}

// ============================================================ PHASE 1 ======
// blocks [0, gc):      rank-count — 1 edge/thread (full grid = max resident
//                      waves = max outstanding atomics; round-5 lesson).
// blocks [gc, gc+gx):  x -> bf16 (float4 -> ushort4)
// blocks [gc+gx, +8):  W -> bf16 transposed to [n][k]
// All parts flat & independent; cvt BW work hides under atomic latency.
__global__ __launch_bounds__(BLK) void k_phase1(
        const int* __restrict__ src, const int* __restrict__ dst,
        int* __restrict__ cnt_f, int* __restrict__ cnt_b,
        int* __restrict__ rank_f, int* __restrict__ rank_b, int ne,
        const float4* __restrict__ x4, ushort4* __restrict__ xb4, int total4,
        const float* __restrict__ Wf, const float* __restrict__ Wb,
        unsigned short* __restrict__ WTf, unsigned short* __restrict__ WTb,
        int gc, int gx) {
    const int bid = blockIdx.x;
    if (bid < gc) {
        int e = bid * BLK + threadIdx.x;
        if (e < ne) {
            int d = dst[e], s = src[e];
            rank_f[e] = atomicAdd(cnt_f + d, 1);
            rank_b[e] = atomicAdd(cnt_b + s, 1);
        }
        return;
    }
    if (bid < gc + gx) {
        int i = (bid - gc) * BLK + threadIdx.x;
        if (i < total4) {
            float4 v = x4[i];
            ushort4 o;
            o.x = f2bf(v.x); o.y = f2bf(v.y); o.z = f2bf(v.z); o.w = f2bf(v.w);
            xb4[i] = o;
        }
        return;
    }
    int wb = bid - gc - gx;                      // 0..7
    for (int idx = wb * 2048 + threadIdx.x; idx < (wb + 1) * 2048; idx += BLK) {
        int c = idx >> 7, k = idx & 127;
        WTf[c * 128 + k] = f2bf(Wf[k * 128 + c]);
        WTb[c * 128 + k] = f2bf(Wb[k * 128 + c]);
    }
}

// ============================================= scan level 1 (+ rsqrt) ======
// flat: 2*nb blocks, 1024 elements each. NO serial loops (round-6 lesson:
// a serial block in a wide dispatch stalls the whole GPU for its duration).
__global__ __launch_bounds__(BLK) void k_scan1(const int* __restrict__ cnt_f,
                                               const int* __restrict__ cnt_b,
                                               int* __restrict__ off_f,
                                               int* __restrict__ off_b,
                                               float* __restrict__ dinv_f,
                                               float* __restrict__ dinv_b,
                                               int* __restrict__ bsum_f,
                                               int* __restrict__ bsum_b,
                                               int n, int nb) {
    const int half = blockIdx.x / nb;
    const int blk  = blockIdx.x % nb;
    const int* __restrict__ in = half ? cnt_b : cnt_f;
    int* __restrict__ out      = half ? off_b : off_f;
    float* __restrict__ dinv   = half ? dinv_b : dinv_f;
    int* __restrict__ bsum     = half ? bsum_b : bsum_f;

    __shared__ int lds[BLK];
    int base = blk * 1024 + threadIdx.x * 4;
    int4 v = make_int4(0, 0, 0, 0);
    if (base < n) v = *(const int4*)(in + base);          // n % 4 == 0
    int tsum = v.x + v.y + v.z + v.w;
    lds[threadIdx.x] = tsum;
    __syncthreads();
    for (int off = 1; off < BLK; off <<= 1) {
        int t = (threadIdx.x >= off) ? lds[threadIdx.x - off] : 0;
        __syncthreads();
        lds[threadIdx.x] += t;
        __syncthreads();
    }
    int excl = lds[threadIdx.x] - tsum;
    if (base < n) {
        *(int4*)(out + base) = make_int4(excl, excl + v.x, excl + v.x + v.y,
                                         excl + v.x + v.y + v.z);
        *(float4*)(dinv + base) = make_float4(rsqrtf(1.0f + (float)v.x),
                                              rsqrtf(1.0f + (float)v.y),
                                              rsqrtf(1.0f + (float)v.z),
                                              rsqrtf(1.0f + (float)v.w));
    }
    if (threadIdx.x == BLK - 1) bsum[blk] = excl + tsum;
}

// ============================================================ scan 2 =======
__global__ __launch_bounds__(BLK) void k_scan2(int* __restrict__ bsum_f,
                                               int* __restrict__ bsum_b, int nb) {
    int* __restrict__ bsum = blockIdx.x ? bsum_b : bsum_f;
    __shared__ int lds[BLK];
    int v = (threadIdx.x < nb) ? bsum[threadIdx.x] : 0;
    lds[threadIdx.x] = v;
    __syncthreads();
    for (int off = 1; off < BLK; off <<= 1) {
        int t = (threadIdx.x >= off) ? lds[threadIdx.x - off] : 0;
        __syncthreads();
        lds[threadIdx.x] += t;
        __syncthreads();
    }
    if (threadIdx.x < nb) bsum[threadIdx.x] = lds[threadIdx.x] - v;
}

// ============================================================ scan 3 =======
__global__ __launch_bounds__(BLK) void k_scan3(int* __restrict__ off_f,
                                               int* __restrict__ off_b,
                                               const int* __restrict__ bsum_f,
                                               const int* __restrict__ bsum_b,
                                               int n, int ne, int gn) {
    const int half = blockIdx.x / gn;
    const int blk  = blockIdx.x % gn;
    int* __restrict__ off        = half ? off_b : off_f;
    const int* __restrict__ bsum = half ? bsum_b : bsum_f;
    int i = blk * BLK + threadIdx.x;
    if (i < n) off[i] += bsum[i >> 10];
    if (i == 0) off[n] = ne;
}

// ============================================================ PHASE 3 ======
// blocks [0, gc):      CSR fill — atomic-free (rank trick), scatter-latency
//                      bound, VALU idle.
// blocks [gc, gc+gg):  MFMA GEMM hs = bf16(dinv * (xb @ W)) — MFMA/LDS
//                      bound. Co-resident waves overlap the two pipes (m114).
__global__ __launch_bounds__(BLK) void k_phase3(
        const int* __restrict__ src, const int* __restrict__ dst,
        const int* __restrict__ off_f, const int* __restrict__ off_b,
        const int* __restrict__ rank_f, const int* __restrict__ rank_b,
        int* __restrict__ adj_f, int* __restrict__ adj_b, int ne,
        const unsigned short* __restrict__ xb,
        const unsigned short* __restrict__ WTf,
        const unsigned short* __restrict__ WTb,
        const float* __restrict__ dinv_f, const float* __restrict__ dinv_b,
        unsigned short* __restrict__ hs_f, unsigned short* __restrict__ hs_b,
        int n, int gc) {
    const int bid = blockIdx.x;
    if (bid < gc) {
        int e = bid * BLK + threadIdx.x;
        if (e < ne) {
            int s = src[e], d = dst[e];
            adj_f[off_f[d] + rank_f[e]] = s;
            adj_b[off_b[s] + rank_b[e]] = d;
        }
        return;
    }
    // ---- MFMA GEMM ----
    const int wave = threadIdx.x >> 6;
    const int lane = threadIdx.x & 63;
    const int conv = wave >> 1;
    const int n0   = (wave & 1) * 64;
    const int m0   = (bid - gc) * 16;
    const int q    = lane >> 4;
    const int t16  = lane & 15;

    const unsigned short* __restrict__ WT = conv ? WTb : WTf;
    const float* __restrict__ dinv        = conv ? dinv_b : dinv_f;
    unsigned short* __restrict__ hs       = conv ? hs_b : hs_f;

    int arow = m0 + t16; if (arow >= n) arow = n - 1;
    bf16x8 a[4];
#pragma unroll
    for (int s = 0; s < 4; ++s)
        a[s] = *(const bf16x8*)(xb + (size_t)arow * 128 + s * 32 + q * 8);

    const float4 dv = *(const float4*)(dinv + m0 + q * 4);

#pragma unroll
    for (int t = 0; t < 4; ++t) {
        const unsigned short* wrow = WT + (size_t)(n0 + t * 16 + t16) * 128;
        f32x4 c = {0.f, 0.f, 0.f, 0.f};
#pragma unroll
        for (int s = 0; s < 4; ++s) {
            bf16x8 b = *(const bf16x8*)(wrow + s * 32 + q * 8);
            c = __builtin_amdgcn_mfma_f32_16x16x32_bf16(a[s], b, c, 0, 0, 0);
        }
#pragma unroll
        for (int r = 0; r < 4; ++r) {
            int row = m0 + q * 4 + r;
            if (row < n) {
                float vr = (r == 0 ? dv.x : r == 1 ? dv.y : r == 2 ? dv.z : dv.w);
                hs[(size_t)row * 128 + n0 + t * 16 + t16] = f2bf(c[r] * vr);
            }
        }
    }
}

// ============================================================ gather =======
__global__ __launch_bounds__(BLK) void k_gather(const int* __restrict__ off_f,
                                                const int* __restrict__ adj_f,
                                                const int* __restrict__ off_b,
                                                const int* __restrict__ adj_b,
                                                const uint32_t* __restrict__ hsf,
                                                const uint32_t* __restrict__ hsb,
                                                const float* __restrict__ dinv_f,
                                                const float* __restrict__ dinv_b,
                                                const float* __restrict__ bf,
                                                const float* __restrict__ bb,
                                                float* __restrict__ out, int n) {
    const int wave = threadIdx.x >> 6;
    const int lane = threadIdx.x & 63;
    const int node = blockIdx.x * 4 + wave;
    if (node >= n) return;

    float f0, f1, g0, g1;
    {
        uint32_t u = hsf[(size_t)node * 64 + lane];
        f0 = bf16lo(u); f1 = bf16hi(u);
        int jb = off_f[node], je = off_f[node + 1];
        for (int b = jb; b < je; b += 64) {
            int m = min(64, je - b);
            int idx = (lane < m) ? adj_f[b + lane] : 0;
            int j = 0;
            for (; j + 8 <= m; j += 8) {
                int n0 = __shfl(idx, j + 0), n1 = __shfl(idx, j + 1);
                int n2 = __shfl(idx, j + 2), n3 = __shfl(idx, j + 3);
                int n4 = __shfl(idx, j + 4), n5 = __shfl(idx, j + 5);
                int n6 = __shfl(idx, j + 6), n7 = __shfl(idx, j + 7);
                uint32_t u0 = hsf[(size_t)n0 * 64 + lane];
                uint32_t u1 = hsf[(size_t)n1 * 64 + lane];
                uint32_t u2 = hsf[(size_t)n2 * 64 + lane];
                uint32_t u3 = hsf[(size_t)n3 * 64 + lane];
                uint32_t u4 = hsf[(size_t)n4 * 64 + lane];
                uint32_t u5 = hsf[(size_t)n5 * 64 + lane];
                uint32_t u6 = hsf[(size_t)n6 * 64 + lane];
                uint32_t u7 = hsf[(size_t)n7 * 64 + lane];
                f0 += bf16lo(u0) + bf16lo(u1) + bf16lo(u2) + bf16lo(u3)
                    + bf16lo(u4) + bf16lo(u5) + bf16lo(u6) + bf16lo(u7);
                f1 += bf16hi(u0) + bf16hi(u1) + bf16hi(u2) + bf16hi(u3)
                    + bf16hi(u4) + bf16hi(u5) + bf16hi(u6) + bf16hi(u7);
            }
            for (; j + 4 <= m; j += 4) {
                int n0 = __shfl(idx, j + 0), n1 = __shfl(idx, j + 1);
                int n2 = __shfl(idx, j + 2), n3 = __shfl(idx, j + 3);
                uint32_t u0 = hsf[(size_t)n0 * 64 + lane];
                uint32_t u1 = hsf[(size_t)n1 * 64 + lane];
                uint32_t u2 = hsf[(size_t)n2 * 64 + lane];
                uint32_t u3 = hsf[(size_t)n3 * 64 + lane];
                f0 += bf16lo(u0) + bf16lo(u1) + bf16lo(u2) + bf16lo(u3);
                f1 += bf16hi(u0) + bf16hi(u1) + bf16hi(u2) + bf16hi(u3);
            }
            for (; j < m; ++j) {
                uint32_t uj = hsf[(size_t)__shfl(idx, j) * 64 + lane];
                f0 += bf16lo(uj); f1 += bf16hi(uj);
            }
        }
        float s = dinv_f[node];
        f0 *= s; f1 *= s;
    }
    {
        uint32_t u = hsb[(size_t)node * 64 + lane];
        g0 = bf16lo(u); g1 = bf16hi(u);
        int jb = off_b[node], je = off_b[node + 1];
        for (int b = jb; b < je; b += 64) {
            int m = min(64, je - b);
            int idx = (lane < m) ? adj_b[b + lane] : 0;
            int j = 0;
            for (; j + 8 <= m; j += 8) {
                int n0 = __shfl(idx, j + 0), n1 = __shfl(idx, j + 1);
                int n2 = __shfl(idx, j + 2), n3 = __shfl(idx, j + 3);
                int n4 = __shfl(idx, j + 4), n5 = __shfl(idx, j + 5);
                int n6 = __shfl(idx, j + 6), n7 = __shfl(idx, j + 7);
                uint32_t u0 = hsb[(size_t)n0 * 64 + lane];
                uint32_t u1 = hsb[(size_t)n1 * 64 + lane];
                uint32_t u2 = hsb[(size_t)n2 * 64 + lane];
                uint32_t u3 = hsb[(size_t)n3 * 64 + lane];
                uint32_t u4 = hsb[(size_t)n4 * 64 + lane];
                uint32_t u5 = hsb[(size_t)n5 * 64 + lane];
                uint32_t u6 = hsb[(size_t)n6 * 64 + lane];
                uint32_t u7 = hsb[(size_t)n7 * 64 + lane];
                g0 += bf16lo(u0) + bf16lo(u1) + bf16lo(u2) + bf16lo(u3)
                    + bf16lo(u4) + bf16lo(u5) + bf16lo(u6) + bf16lo(u7);
                g1 += bf16hi(u0) + bf16hi(u1) + bf16hi(u2) + bf16hi(u3)
                    + bf16hi(u4) + bf16hi(u5) + bf16hi(u6) + bf16hi(u7);
            }
            for (; j + 4 <= m; j += 4) {
                int n0 = __shfl(idx, j + 0), n1 = __shfl(idx, j + 1);
                int n2 = __shfl(idx, j + 2), n3 = __shfl(idx, j + 3);
                uint32_t u0 = hsb[(size_t)n0 * 64 + lane];
                uint32_t u1 = hsb[(size_t)n1 * 64 + lane];
                uint32_t u2 = hsb[(size_t)n2 * 64 + lane];
                uint32_t u3 = hsb[(size_t)n3 * 64 + lane];
                g0 += bf16lo(u0) + bf16lo(u1) + bf16lo(u2) + bf16lo(u3);
                g1 += bf16hi(u0) + bf16hi(u1) + bf16hi(u2) + bf16hi(u3);
            }
            for (; j < m; ++j) {
                uint32_t uj = hsb[(size_t)__shfl(idx, j) * 64 + lane];
                g0 += bf16lo(uj); g1 += bf16hi(uj);
            }
        }
        float s = dinv_b[node];
        g0 *= s; g1 *= s;
    }

    const float2 biasf = ((const float2*)bf)[lane];
    const float2 biasb = ((const float2*)bb)[lane];
    float v0 = f0 + g0 + biasf.x + biasb.x;
    float v1 = f1 + g1 + biasf.y + biasb.y;
    ((float2*)out)[(size_t)node * 64 + lane] =
        make_float2(fmaxf(v0, 0.0f), fmaxf(v1, 0.0f));
}

// ============================================================ launcher =====
extern "C" void kernel_launch(void* const* d_in, const int* in_sizes, int n_in,
                              void* d_out, int out_size, void* d_ws, size_t ws_size,
                              hipStream_t stream) {
    const float* x  = (const float*)d_in[0];
    const int*   ei = (const int*)d_in[1];
    const float* Wf = (const float*)d_in[2];
    const float* bf = (const float*)d_in[3];
    const float* Wb = (const float*)d_in[4];
    const float* bb = (const float*)d_in[5];

    const int n  = in_sizes[0] / 128;   // 50000
    const int ne = in_sizes[1] / 2;     // 625000
    const int* src = ei;
    const int* dst = ei + ne;
    float* out = (float*)d_out;

    // workspace layout (16B-aligned; n, ne multiples of 4)
    char* w = (char*)d_ws;
    float* dinv_f = (float*)w;                      w += (size_t)n * 4;
    float* dinv_b = (float*)w;                      w += (size_t)n * 4;
    unsigned short* hs_f = (unsigned short*)w;      w += (size_t)n * 128 * 2;
    unsigned short* hs_b = (unsigned short*)w;      w += (size_t)n * 128 * 2;
    unsigned short* xb   = (unsigned short*)w;      w += (size_t)n * 128 * 2;
    unsigned short* WTf  = (unsigned short*)w;      w += 128 * 128 * 2;
    unsigned short* WTb  = (unsigned short*)w;      w += 128 * 128 * 2;
    int*   cnt_f  = (int*)w;                        w += (size_t)n * 4;   // contiguous
    int*   cnt_b  = (int*)w;                        w += (size_t)n * 4;   //  with cnt_f
    int*   off_f  = (int*)w;                        w += (size_t)(n + 4) * 4;
    int*   off_b  = (int*)w;                        w += (size_t)(n + 4) * 4;
    int*   rank_f = (int*)w;                        w += (size_t)ne * 4;
    int*   rank_b = (int*)w;                        w += (size_t)ne * 4;
    int*   adj_f  = (int*)w;                        w += (size_t)ne * 4;
    int*   adj_b  = (int*)w;                        w += (size_t)ne * 4;
    int*   bsum_f = (int*)w;                        w += 256 * 4;
    int*   bsum_b = (int*)w;                        w += 256 * 4;

    const int gc = (ne + BLK - 1) / BLK;            // 2442 edge blocks
    const int gn = (n + BLK - 1) / BLK;             // 196 node blocks
    const int nb = (n + 1023) / 1024;               // 49 scan chunks
    const int total4 = n * 32;
    const int gx = (total4 + BLK - 1) / BLK;        // 6250 cvt blocks
    const int gg = (n + 15) / 16;                   // 3125 gemm blocks

    hipMemsetAsync(cnt_f, 0, (size_t)2 * n * 4, stream);

    k_phase1<<<gc + gx + 8, BLK, 0, stream>>>(src, dst, cnt_f, cnt_b,
                                              rank_f, rank_b, ne,
                                              (const float4*)x, (ushort4*)xb, total4,
                                              Wf, Wb, WTf, WTb, gc, gx);

    k_scan1<<<2 * nb, BLK, 0, stream>>>(cnt_f, cnt_b, off_f, off_b,
                                        dinv_f, dinv_b, bsum_f, bsum_b, n, nb);
    k_scan2<<<2, BLK, 0, stream>>>(bsum_f, bsum_b, nb);
    k_scan3<<<2 * gn, BLK, 0, stream>>>(off_f, off_b, bsum_f, bsum_b, n, ne, gn);

    k_phase3<<<gc + gg, BLK, 0, stream>>>(src, dst, off_f, off_b,
                                          rank_f, rank_b, adj_f, adj_b, ne,
                                          xb, WTf, WTb, dinv_f, dinv_b,
                                          hs_f, hs_b, n, gc);

    k_gather<<<(n + 3) / 4, BLK, 0, stream>>>(off_f, adj_f, off_b, adj_b,
                                              (const uint32_t*)hs_f,
                                              (const uint32_t*)hs_b,
                                              dinv_f, dinv_b, bf, bb, out, n);
}